// Round 4
// baseline (539.447 us; speedup 1.0000x reference)
//
#include <hip/hip_runtime.h>
#include <cstdint>

#define N_TOK  32768
#define DIM    1024
#define NEXP   64
#define NTHR   256                 // 4 waves; wave w owns k-slice w
#define TOKB   64                  // tokens per block (one per lane)
#define NBLK   (N_TOK / TOKB)      // 512
#define KS     4
#define KSLICE (DIM / KS)          // 256 floats per k-split
#define NCHUNK (KSLICE / 16)       // 16 chunks of 16 floats (= one 64B line/thread)

__launch_bounds__(NTHR, 2)
__global__ void router_kernel(const float* __restrict__ x,
                              const float* __restrict__ Wg,
                              float* __restrict__ out,
                              float* __restrict__ ws) {
  // ws layout: [0..63] cnt, [64..127] psum, [128] done counter (all pre-zeroed)
  float* cnt_g = ws;
  float* sp_g  = ws + 64;
  unsigned int* done = (unsigned int*)(ws + 128);

  __shared__ float4 cmb[KS][TOKB][16];   // 64 KB, one-time k-split combine
  __shared__ unsigned int lastflag;

  const int tid  = threadIdx.x;
  const int lane = tid & 63;
  // k-split index; readfirstlane => provably wave-uniform => W loads scalarize
  const int w    = __builtin_amdgcn_readfirstlane(tid >> 6);
  const int tok  = blockIdx.x * TOKB + lane;

  const float4* __restrict__ xr = (const float4*)(x + (size_t)tok * DIM + (size_t)w * KSLICE);
  const float4* __restrict__ W4 = (const float4*)Wg;

  float acc[NEXP];
#pragma unroll
  for (int e = 0; e < NEXP; ++e) acc[e] = 0.f;

  // one chunk = 16 k-values for all 64 experts; W via scalar loads (SGPR operand)
  auto chunk = [&](const float4* xv, int c) {
#pragma unroll
    for (int e = 0; e < NEXP; e += 2) {
      const float4* wp0 = W4 + (e * (DIM / 4) + w * (KSLICE / 4) + c * 4);
      const float4* wp1 = wp0 + (DIM / 4);
      float4 wa0 = wp0[0], wa1 = wp0[1], wa2 = wp0[2], wa3 = wp0[3];
      float4 wb0 = wp1[0], wb1 = wp1[1], wb2 = wp1[2], wb3 = wp1[3];
      float A = acc[e], B = acc[e + 1];
      A = fmaf(xv[0].x, wa0.x, A); B = fmaf(xv[0].x, wb0.x, B);
      A = fmaf(xv[0].y, wa0.y, A); B = fmaf(xv[0].y, wb0.y, B);
      A = fmaf(xv[0].z, wa0.z, A); B = fmaf(xv[0].z, wb0.z, B);
      A = fmaf(xv[0].w, wa0.w, A); B = fmaf(xv[0].w, wb0.w, B);
      A = fmaf(xv[1].x, wa1.x, A); B = fmaf(xv[1].x, wb1.x, B);
      A = fmaf(xv[1].y, wa1.y, A); B = fmaf(xv[1].y, wb1.y, B);
      A = fmaf(xv[1].z, wa1.z, A); B = fmaf(xv[1].z, wb1.z, B);
      A = fmaf(xv[1].w, wa1.w, A); B = fmaf(xv[1].w, wb1.w, B);
      A = fmaf(xv[2].x, wa2.x, A); B = fmaf(xv[2].x, wb2.x, B);
      A = fmaf(xv[2].y, wa2.y, A); B = fmaf(xv[2].y, wb2.y, B);
      A = fmaf(xv[2].z, wa2.z, A); B = fmaf(xv[2].z, wb2.z, B);
      A = fmaf(xv[2].w, wa2.w, A); B = fmaf(xv[2].w, wb2.w, B);
      A = fmaf(xv[3].x, wa3.x, A); B = fmaf(xv[3].x, wb3.x, B);
      A = fmaf(xv[3].y, wa3.y, A); B = fmaf(xv[3].y, wb3.y, B);
      A = fmaf(xv[3].z, wa3.z, A); B = fmaf(xv[3].z, wb3.z, B);
      A = fmaf(xv[3].w, wa3.w, A); B = fmaf(xv[3].w, wb3.w, B);
      acc[e] = A; acc[e + 1] = B;
    }
  };

  // register-double-buffered x (1 chunk = 4 float4 = one 64B line per thread)
  float4 xa[4], xb[4];
#pragma unroll
  for (int q = 0; q < 4; ++q) xa[q] = xr[q];

  for (int c = 0; c < NCHUNK; c += 2) {
#pragma unroll
    for (int q = 0; q < 4; ++q) xb[q] = xr[(c + 1) * 4 + q];
    chunk(xa, c);
    if (c + 2 < NCHUNK) {
#pragma unroll
      for (int q = 0; q < 4; ++q) xa[q] = xr[(c + 2) * 4 + q];
    }
    chunk(xb, c + 1);
  }

  // ---- k-split combine via LDS (XOR-swizzled float4 slots: conflict-spread) ----
#pragma unroll
  for (int q = 0; q < 16; ++q) {
    float4 v;
    v.x = acc[4 * q]; v.y = acc[4 * q + 1]; v.z = acc[4 * q + 2]; v.w = acc[4 * q + 3];
    cmb[w][lane][q ^ (lane & 15)] = v;
  }
  __syncthreads();

  if (tid < 64) {   // wave 0: one lane per token
    float lg[NEXP];
#pragma unroll
    for (int q = 0; q < 16; ++q) {
      const int qs = q ^ (lane & 15);
      float4 s0 = cmb[0][lane][qs];
      float4 s1 = cmb[1][lane][qs];
      float4 s2 = cmb[2][lane][qs];
      float4 s3 = cmb[3][lane][qs];
      lg[4 * q]     = s0.x + s1.x + s2.x + s3.x;
      lg[4 * q + 1] = s0.y + s1.y + s2.y + s3.y;
      lg[4 * q + 2] = s0.z + s1.z + s2.z + s3.z;
      lg[4 * q + 3] = s0.w + s1.w + s2.w + s3.w;
    }

    // top-2 (strict >: lowest-index tie-break, matches lax.top_k)
    float v1 = lg[0]; int t1 = 0;
    float v2 = -3.4e38f; int t2 = 0;
#pragma unroll
    for (int e = 1; e < NEXP; ++e) {
      float v = lg[e];
      if (v > v1)      { v2 = v1; t2 = t1; v1 = v; t1 = e; }
      else if (v > v2) { v2 = v;  t2 = e; }
    }

    // softmax numerators + sum
    float ssum = 0.f;
#pragma unroll
    for (int e = 0; e < NEXP; ++e) { float p = __expf(lg[e] - v1); lg[e] = p; ssum += p; }
    const float inv = 1.f / ssum;

    // outputs
    const float e2v = __expf(v2 - v1);
    const float r   = 1.f / (1.f + e2v);       // p1/(p1+p2)
    out[2 * tok]     = r;
    out[2 * tok + 1] = e2v * r;
    out[2 * N_TOK + 2 * tok]     = (float)t1;
    out[2 * N_TOK + 2 * tok + 1] = (float)t2;

    // per-expert prob sums over this block's 64 tokens; lane e ends with expert e
    float myps = 0.f;
#pragma unroll
    for (int e = 0; e < NEXP; ++e) {
      float s = lg[e] * inv;
      s += __shfl_xor(s, 1);  s += __shfl_xor(s, 2);  s += __shfl_xor(s, 4);
      s += __shfl_xor(s, 8);  s += __shfl_xor(s, 16); s += __shfl_xor(s, 32);
      if (lane == e) myps = s;
    }
    // per-expert top-2 counts via ballot; lane e keeps expert e
    float myc = 0.f;
#pragma unroll
    for (int e = 0; e < NEXP; ++e) {
      unsigned long long m1 = __ballot(t1 == e);
      unsigned long long m2 = __ballot(t2 == e);
      if (lane == e) myc = (float)(__popcll(m1) + __popcll(m2));
    }
    atomicAdd(&sp_g[lane], myps);
    atomicAdd(&cnt_g[lane], myc);
  }

  // ---- last finishing block computes aux_loss in-kernel ----
  if (tid == 0) {
    __threadfence();                              // drain this wave's atomics, release
    lastflag = (atomicAdd(done, 1u) == NBLK - 1) ? 1u : 0u;
  }
  __syncthreads();
  if (lastflag && tid < 64) {
    float C = atomicAdd(&cnt_g[lane], 0.f);       // coherent (L2) load
    float S = atomicAdd(&sp_g[lane], 0.f);
    float v = C * S;
    v += __shfl_xor(v, 1);  v += __shfl_xor(v, 2);  v += __shfl_xor(v, 4);
    v += __shfl_xor(v, 8);  v += __shfl_xor(v, 16); v += __shfl_xor(v, 32);
    if (lane == 0)
      out[4 * N_TOK] = (float)NEXP * v * (1.f / (float)N_TOK) * (1.f / (float)N_TOK);
  }
}

extern "C" void kernel_launch(void* const* d_in, const int* in_sizes, int n_in,
                              void* d_out, int out_size, void* d_ws, size_t ws_size,
                              hipStream_t stream) {
  const float* x  = (const float*)d_in[0];
  const float* Wg = (const float*)d_in[1];
  float* out = (float*)d_out;

  hipMemsetAsync(d_ws, 0, 1024, stream);   // zero cnt[64] + psum[64] + done
  router_kernel<<<dim3(NBLK), dim3(NTHR), 0, stream>>>(x, Wg, out, (float*)d_ws);
}